// Round 6
// baseline (26567.151 us; speedup 1.0000x reference)
//
#include <hip/hip_runtime.h>
#include <stdint.h>

#define TT    512
#define HID   1024
#define G4    4096
#define INDIM 85
#define NOUT  20670   // 6890*3

typedef unsigned long long u64;
typedef unsigned int u32;

// ---------------------------------------------------------------------------
// Tiled fp32 GEMM: C[M,N] = A[M,K] * B[N,K]^T + bias0 + bias1
// 64x64 tile, BK=16, 256 threads, 4x4 micro-tile per thread. (unchanged)
// ---------------------------------------------------------------------------
__global__ __launch_bounds__(256)
void gemm_nt(const float* __restrict__ A, const float* __restrict__ B,
             const float* __restrict__ bias0, const float* __restrict__ bias1,
             float* __restrict__ C, int M, int N, int K)
{
    __shared__ float As[16 * 68];
    __shared__ float Bs[16 * 68];
    const int tid = threadIdx.x;
    const int tx = tid & 15, ty = tid >> 4;
    const int m0 = blockIdx.y * 64, n0 = blockIdx.x * 64;
    float acc[4][4] = {};
    const int KT = (K + 15) >> 4;

    for (int kt = 0; kt < KT; ++kt) {
        const int k0 = kt << 4;
        __syncthreads();
        for (int l = tid; l < 1024; l += 256) {
            const int mm = l >> 4, kk = l & 15;
            const int kg = k0 + kk;
            As[kk * 68 + mm] = (kg < K) ? A[(size_t)(m0 + mm) * K + kg] : 0.f;
            Bs[kk * 68 + mm] = (kg < K && (n0 + mm) < N)
                                   ? B[(size_t)(n0 + mm) * K + kg] : 0.f;
        }
        __syncthreads();
        #pragma unroll
        for (int kk = 0; kk < 16; ++kk) {
            const float4 av = *(const float4*)&As[kk * 68 + ty * 4];
            const float4 bv = *(const float4*)&Bs[kk * 68 + tx * 4];
            const float a[4] = {av.x, av.y, av.z, av.w};
            const float b[4] = {bv.x, bv.y, bv.z, bv.w};
            #pragma unroll
            for (int i = 0; i < 4; ++i)
                #pragma unroll
                for (int j = 0; j < 4; ++j)
                    acc[i][j] += a[i] * b[j];
        }
    }

    float bj[4];
    #pragma unroll
    for (int j = 0; j < 4; ++j) {
        const int n = n0 + tx * 4 + j;
        float bv = 0.f;
        if (n < N) {
            if (bias0) bv += bias0[n];
            if (bias1) bv += bias1[n];
        }
        bj[j] = bv;
    }
    #pragma unroll
    for (int i = 0; i < 4; ++i) {
        const int m = m0 + ty * 4 + i;
        #pragma unroll
        for (int j = 0; j < 4; ++j) {
            const int n = n0 + tx * 4 + j;
            if (n < N) C[(size_t)m * N + n] = acc[i][j] + bj[j];
        }
    }
}

// ---------------------------------------------------------------------------
// Fused 3-layer pipelined LSTM scan. 768 blocks x 256 threads, 3 blocks/CU.
//   layer = blockIdx>>8, b = blockIdx&255; block owns units u0=4b..4b+3.
//
// ROUND-6 (theory G: detection-cascade / straggler amplification). R0/R1/R5
// all sat at 8.15us/step across three DIFFERENT poll mechanics -> poll
// mechanics exonerated. The invariant is the topology: 256 threads/block
// each independently detecting their own quad (independent sleep phases) =>
// block proceeds at max-of-256 detections (~mean*ln256), compounded by the
// max-of-256-blocks producer spread each step. Fix: single-point detection +
// broadcast:
//  * producers publish quads (as before) then ONE lane release-adds a group
//    counter (16 groups x 16 blocks -> 16 serialized RMWs/line ~ 0.25us).
//  * block b=0 of each layer (already resident; no new blocks -> no
//    deadlock) polls the 16 counters with 16 lanes (ONE poller per line),
//    then broadcasts per-consumer-block flags (256 u32, release).
//  * consumers: ONE lane polls ONE flag (own layer) + one lane the input
//    flag; then ALL threads bulk plain-read h rows (first touch after
//    publish -> fresh L3 fill), tag-verify, atomic fallback (R5 machinery).
//  * epilogue: b=0 of layers 0,1 writes the final flag for t=TT-1 so the
//    upper layer's last step cannot starve.
// Acquire/release chain: quad stores -> release-add -> acquire counter poll
// -> release flag store -> acquire flag poll -> plain read; tag-verify +
// atomic fallback backstops any residual staleness.
// ---------------------------------------------------------------------------
__device__ __forceinline__ float sig_(float x) { return 1.f / (1.f + expf(-x)); }

__global__ __launch_bounds__(256, 3)
void lstm_fused(const float* __restrict__ xg,
                const float* __restrict__ Whh0,
                const float* __restrict__ Wih1, const float* __restrict__ Whh1,
                const float* __restrict__ bih1, const float* __restrict__ bhh1,
                const float* __restrict__ Wih2, const float* __restrict__ Whh2,
                const float* __restrict__ bih2, const float* __restrict__ bhh2,
                u64* __restrict__ hbuf0, u64* __restrict__ hbuf1,
                u64* __restrict__ hbuf2, u32* __restrict__ cnt,
                u32* __restrict__ flg, float* __restrict__ hs2)
{
    __shared__ float hin_lds[HID];
    __shared__ float hprev_lds[HID];
    __shared__ float gsum[4][4];   // [wave/unit][gate]

    const int tid = threadIdx.x;
    const int w = tid >> 6, ln = tid & 63, q = ln & 31;
    const bool inHalf = (ln < 32);
    const int layer = blockIdx.x >> 8;
    const int b = blockIdx.x & 255;
    const int u0 = 4 * b;
    const int unit = u0 + w;

    const float* Wih = (layer == 1) ? Wih1 : Wih2;                 // unused for layer 0
    const float* Whh = (layer == 0) ? Whh0 : (layer == 1 ? Whh1 : Whh2);
    u64* hbI = (layer == 1) ? hbuf0 : hbuf1;                        // input-h buffer (layers 1,2)
    u64* hbP = (layer == 0) ? hbuf0 : (layer == 1 ? hbuf1 : hbuf2); // own-layer buffer

    // ---- stage weights: 4 gate-rows x 32 cols of one matrix per lane ----
    float4 Wv[4][8];
    if (layer == 0 && inHalf) {
        #pragma unroll
        for (int g = 0; g < 4; ++g)
            #pragma unroll
            for (int j = 0; j < 8; ++j)
                Wv[g][j] = make_float4(0.f, 0.f, 0.f, 0.f);
    } else {
        const float* M = inHalf ? Wih : Whh;
        #pragma unroll
        for (int g = 0; g < 4; ++g) {
            const float* rp = M + (size_t)(g * HID + unit) * HID + 4 * q;
            #pragma unroll
            for (int j = 0; j < 8; ++j)
                Wv[g][j] = *(const float4*)(rp + 128 * j);
        }
    }

    // per-gate additive term: WAVE 0 LANES 0..3, lane ln handles unit u0+ln.
    float add4[4] = {0.f, 0.f, 0.f, 0.f};
    if (w == 0 && ln < 4 && layer > 0) {
        #pragma unroll
        for (int g = 0; g < 4; ++g) {
            const int r = g * HID + u0 + ln;
            add4[g] = (layer == 1) ? (bih1[r] + bhh1[r]) : (bih2[r] + bhh2[r]);
        }
    }

    if (layer == 0) {   // W_ih half unused: keep hin_lds at exact zeros
        const int p4z = 4 * ((tid + b) & 255);
        *(float4*)&hin_lds[p4z] = make_float4(0.f, 0.f, 0.f, 0.f);
    }

    float c = 0.f;   // cell state in wave-0 lanes 0..3
    for (int t = 0; t < TT; ++t) {
        if (layer == 0 && w == 0 && ln < 4) {   // x-gates prefetch (pre-poll)
            #pragma unroll
            for (int g = 0; g < 4; ++g)
                add4[g] = xg[(size_t)t * G4 + g * HID + u0 + ln];
        }

        // ---- block 0: aggregate own-layer step t-1 and broadcast flags ----
        if (b == 0 && t > 0 && w == 0) {
            if (ln < 16) {
                const u32* ca = cnt + ((size_t)(layer * TT + (t - 1)) * 16 + ln) * 16;
                int guard = 0;
                while (__hip_atomic_load(ca, __ATOMIC_ACQUIRE,
                                         __HIP_MEMORY_SCOPE_AGENT) < 16u) {
                    if (++guard > (1 << 18)) break;   // anti-hang bailout
                    __builtin_amdgcn_s_sleep(1);
                }
            }
            // broadcast: 256 per-consumer-block flags (4 coalesced stores/lane)
            u32* fp = flg + (size_t)(layer * TT + (t - 1)) * 256;
            #pragma unroll
            for (int r = 0; r < 4; ++r)
                __hip_atomic_store(fp + r * 64 + ln, 1u,
                                   __ATOMIC_RELEASE, __HIP_MEMORY_SCOPE_AGENT);
        }

        // ---- single-point detection: lane0 own flag, lane1 input flag ----
        if (w == 0) {
            const u32* fa = nullptr;
            if (ln == 0 && t > 0 && b != 0)
                fa = flg + (size_t)(layer * TT + (t - 1)) * 256 + b;
            else if (ln == 1 && layer > 0)
                fa = flg + (size_t)((layer - 1) * TT + t) * 256 + b;
            bool done = (fa == nullptr);
            int guard = 0;
            while (!__all(done)) {
                if (!done)
                    done = __hip_atomic_load(fa, __ATOMIC_ACQUIRE,
                                             __HIP_MEMORY_SCOPE_AGENT) != 0u;
                if (++guard > (1 << 18)) break;   // anti-hang bailout
                if (!__all(done)) __builtin_amdgcn_s_sleep(1);
            }
        }
        __syncthreads();   // (0) readiness broadcast to whole block

        // ---- bulk h read: plain cached loads + tag verify + fallback ----
        const int p4 = 4 * ((tid + b) & 255);
        const u32 tP32 = (u32)t;                    // hbP[t-1] carries tag t
        const u32 tI32 = (u32)(t + 1);              // hbI[t]   carries tag t+1
        u64 vp0 = 0, vp1 = 0, vp2 = 0, vp3 = 0;
        u64 vi0 = 0, vi1 = 0, vi2 = 0, vi3 = 0;
        if (t > 0) {
            const u64* pp = hbP + (size_t)(t - 1) * HID + p4;
            uint4 a  = *(const uint4*)(pp);
            uint4 b2 = *(const uint4*)(pp + 2);
            if (!(a.y == tP32 && a.w == tP32 && b2.y == tP32 && b2.w == tP32)) {
                int guard = 0;                      // fallback: atomic re-read
                for (;;) {
                    const u64 q0 = __hip_atomic_load(pp + 0, __ATOMIC_RELAXED, __HIP_MEMORY_SCOPE_AGENT);
                    const u64 q1 = __hip_atomic_load(pp + 1, __ATOMIC_RELAXED, __HIP_MEMORY_SCOPE_AGENT);
                    const u64 q2 = __hip_atomic_load(pp + 2, __ATOMIC_RELAXED, __HIP_MEMORY_SCOPE_AGENT);
                    const u64 q3 = __hip_atomic_load(pp + 3, __ATOMIC_RELAXED, __HIP_MEMORY_SCOPE_AGENT);
                    if ((q0 >> 32) == tP32 && (q1 >> 32) == tP32 &&
                        (q2 >> 32) == tP32 && (q3 >> 32) == tP32) {
                        a.x = (u32)q0; a.z = (u32)q1; b2.x = (u32)q2; b2.z = (u32)q3;
                        break;
                    }
                    if (++guard > (1 << 18)) break;
                    __builtin_amdgcn_s_sleep(1);
                }
            }
            vp0 = a.x; vp1 = a.z; vp2 = b2.x; vp3 = b2.z;
        }
        if (layer > 0) {
            const u64* pi = hbI + (size_t)t * HID + p4;
            uint4 a  = *(const uint4*)(pi);
            uint4 b2 = *(const uint4*)(pi + 2);
            if (!(a.y == tI32 && a.w == tI32 && b2.y == tI32 && b2.w == tI32)) {
                int guard = 0;
                for (;;) {
                    const u64 q0 = __hip_atomic_load(pi + 0, __ATOMIC_RELAXED, __HIP_MEMORY_SCOPE_AGENT);
                    const u64 q1 = __hip_atomic_load(pi + 1, __ATOMIC_RELAXED, __HIP_MEMORY_SCOPE_AGENT);
                    const u64 q2 = __hip_atomic_load(pi + 2, __ATOMIC_RELAXED, __HIP_MEMORY_SCOPE_AGENT);
                    const u64 q3 = __hip_atomic_load(pi + 3, __ATOMIC_RELAXED, __HIP_MEMORY_SCOPE_AGENT);
                    if ((q0 >> 32) == tI32 && (q1 >> 32) == tI32 &&
                        (q2 >> 32) == tI32 && (q3 >> 32) == tI32) {
                        a.x = (u32)q0; a.z = (u32)q1; b2.x = (u32)q2; b2.z = (u32)q3;
                        break;
                    }
                    if (++guard > (1 << 18)) break;
                    __builtin_amdgcn_s_sleep(1);
                }
            }
            vi0 = a.x; vi1 = a.z; vi2 = b2.x; vi3 = b2.z;
        }

        if (t == 0)
            *(float4*)&hprev_lds[p4] = make_float4(0.f, 0.f, 0.f, 0.f);
        else
            *(float4*)&hprev_lds[p4] = make_float4(
                __uint_as_float((unsigned)vp0), __uint_as_float((unsigned)vp1),
                __uint_as_float((unsigned)vp2), __uint_as_float((unsigned)vp3));
        if (layer > 0)
            *(float4*)&hin_lds[p4] = make_float4(
                __uint_as_float((unsigned)vi0), __uint_as_float((unsigned)vi1),
                __uint_as_float((unsigned)vi2), __uint_as_float((unsigned)vi3));
        __syncthreads();   // (1) h vectors staged

        // ---- matvec: 4 gate rows x 32 cols, weights in regs, h from LDS ----
        const float* hsrc = (inHalf ? hin_lds : hprev_lds) + 4 * q;
        float a0 = 0.f, a1 = 0.f, a2 = 0.f, a3 = 0.f;
        #pragma unroll
        for (int j = 0; j < 8; ++j) {
            const float4 hv = *(const float4*)(hsrc + 128 * j);
            a0 += Wv[0][j].x * hv.x + Wv[0][j].y * hv.y + Wv[0][j].z * hv.z + Wv[0][j].w * hv.w;
            a1 += Wv[1][j].x * hv.x + Wv[1][j].y * hv.y + Wv[1][j].z * hv.z + Wv[1][j].w * hv.w;
            a2 += Wv[2][j].x * hv.x + Wv[2][j].y * hv.y + Wv[2][j].z * hv.z + Wv[2][j].w * hv.w;
            a3 += Wv[3][j].x * hv.x + Wv[3][j].y * hv.y + Wv[3][j].z * hv.z + Wv[3][j].w * hv.w;
        }
        // 64-lane butterfly: sums ih-partials (lanes<32) + hh-partials (>=32)
        #pragma unroll
        for (int off = 1; off < 64; off <<= 1) {
            a0 += __shfl_xor(a0, off, 64);
            a1 += __shfl_xor(a1, off, 64);
            a2 += __shfl_xor(a2, off, 64);
            a3 += __shfl_xor(a3, off, 64);
        }
        if (ln == 0) {
            gsum[w][0] = a0; gsum[w][1] = a1; gsum[w][2] = a2; gsum[w][3] = a3;
        }
        __syncthreads();   // (2) gate sums exchanged; LDS safe to overwrite next iter

        // ---- wave 0 lanes 0..3: elementwise + quad publish + counter add ----
        if (w == 0 && ln < 4) {
            const float i_ = sig_(gsum[ln][0] + add4[0]);
            const float f_ = sig_(gsum[ln][1] + add4[1]);
            const float g_ = tanhf(gsum[ln][2] + add4[2]);
            const float o_ = sig_(gsum[ln][3] + add4[3]);
            c = f_ * c + i_ * g_;
            const float h = o_ * tanhf(c);
            if (layer == 2) hs2[(size_t)t * HID + u0 + ln] = h;
            const u64 pv = (((u64)(unsigned)(t + 1)) << 32) |
                           (u64)__float_as_uint(h);
            __hip_atomic_store(hbP + (size_t)t * HID + u0 + ln, pv,
                               __ATOMIC_RELAXED, __HIP_MEMORY_SCOPE_AGENT);
            if (ln == 0) {
                // RELEASE orders the wave's quad stores before the count.
                __hip_atomic_fetch_add(
                    cnt + ((size_t)(layer * TT + t) * 16 + (b >> 4)) * 16, 1u,
                    __ATOMIC_RELEASE, __HIP_MEMORY_SCOPE_AGENT);
            }
        }
    }

    // ---- epilogue: final input-flag broadcast for t=TT-1 (layers 0,1) ----
    if (b == 0 && layer < 2 && w == 0) {
        if (ln < 16) {
            const u32* ca = cnt + ((size_t)(layer * TT + (TT - 1)) * 16 + ln) * 16;
            int guard = 0;
            while (__hip_atomic_load(ca, __ATOMIC_ACQUIRE,
                                     __HIP_MEMORY_SCOPE_AGENT) < 16u) {
                if (++guard > (1 << 18)) break;
                __builtin_amdgcn_s_sleep(1);
            }
        }
        u32* fp = flg + (size_t)(layer * TT + (TT - 1)) * 256;
        #pragma unroll
        for (int r = 0; r < 4; ++r)
            __hip_atomic_store(fp + r * 64 + ln, 1u,
                               __ATOMIC_RELEASE, __HIP_MEMORY_SCOPE_AGENT);
    }
}

// ---------------------------------------------------------------------------
extern "C" void kernel_launch(void* const* d_in, const int* in_sizes, int n_in,
                              void* d_out, int out_size, void* d_ws, size_t ws_size,
                              hipStream_t stream)
{
    (void)in_sizes; (void)n_in; (void)out_size; (void)ws_size;

    const float* pose = (const float*)d_in[0];
    const float* Wih0 = (const float*)d_in[1];
    const float* Whh0 = (const float*)d_in[2];
    const float* bih0 = (const float*)d_in[3];
    const float* bhh0 = (const float*)d_in[4];
    const float* Wih1 = (const float*)d_in[5];
    const float* Whh1 = (const float*)d_in[6];
    const float* bih1 = (const float*)d_in[7];
    const float* bhh1 = (const float*)d_in[8];
    const float* Wih2 = (const float*)d_in[9];
    const float* Whh2 = (const float*)d_in[10];
    const float* bih2 = (const float*)d_in[11];
    const float* bhh2 = (const float*)d_in[12];
    const float* Wout = (const float*)d_in[13];
    float* out = (float*)d_out;

    // Workspace: hbuf0|1|2 (3x4MB) | cnt (1.5MB) | flg (1.5MB) | xg (8MB) | hs2 (2MB)
    char* ws = (char*)d_ws;
    const size_t HB  = (size_t)TT * HID * sizeof(u64);
    const size_t CNT = (size_t)3 * TT * 16 * 16 * sizeof(u32);
    const size_t FLG = (size_t)3 * TT * 256 * sizeof(u32);
    u64* hbuf0 = (u64*)ws;
    u64* hbuf1 = (u64*)(ws + HB);
    u64* hbuf2 = (u64*)(ws + 2 * HB);
    u32* cnt   = (u32*)(ws + 3 * HB);
    u32* flg   = (u32*)(ws + 3 * HB + CNT);
    float* xg  = (float*)(ws + 3 * HB + CNT + FLG);
    float* hs2 = (float*)(ws + 3 * HB + CNT + FLG + (size_t)TT * G4 * sizeof(float));

    (void)hipMemsetAsync(hbuf0, 0, 3 * HB + CNT + FLG, stream);

    const dim3 blk(256);
    // layer-0 x-gates: [512,85] x [85,4096]^T (+ both biases)
    gemm_nt<<<dim3(G4 / 64, TT / 64), blk, 0, stream>>>(
        pose, Wih0, bih0, bhh0, xg, TT, G4, INDIM);
    // fused pipelined 3-layer scan
    lstm_fused<<<dim3(768), blk, 0, stream>>>(
        xg, Whh0, Wih1, Whh1, bih1, bhh1, Wih2, Whh2, bih2, bhh2,
        hbuf0, hbuf1, hbuf2, cnt, flg, hs2);
    // output projection: [512,1024] x [1024,20670]^T
    gemm_nt<<<dim3((NOUT + 63) / 64, TT / 64), blk, 0, stream>>>(
        hs2, Wout, nullptr, nullptr, out, TT, NOUT, HID);
}

// Round 7
// 6141.612 us; speedup vs baseline: 4.3258x; 4.3258x over previous
//
#include <hip/hip_runtime.h>
#include <stdint.h>

#define TT    512
#define HID   1024
#define G4    4096
#define INDIM 85
#define NOUT  20670   // 6890*3

typedef unsigned long long u64;
typedef unsigned int u32;

// ---------------------------------------------------------------------------
// Tiled fp32 GEMM: C[M,N] = A[M,K] * B[N,K]^T + bias0 + bias1
// 64x64 tile, BK=16, 256 threads, 4x4 micro-tile per thread. (unchanged)
// ---------------------------------------------------------------------------
__global__ __launch_bounds__(256)
void gemm_nt(const float* __restrict__ A, const float* __restrict__ B,
             const float* __restrict__ bias0, const float* __restrict__ bias1,
             float* __restrict__ C, int M, int N, int K)
{
    __shared__ float As[16 * 68];
    __shared__ float Bs[16 * 68];
    const int tid = threadIdx.x;
    const int tx = tid & 15, ty = tid >> 4;
    const int m0 = blockIdx.y * 64, n0 = blockIdx.x * 64;
    float acc[4][4] = {};
    const int KT = (K + 15) >> 4;

    for (int kt = 0; kt < KT; ++kt) {
        const int k0 = kt << 4;
        __syncthreads();
        for (int l = tid; l < 1024; l += 256) {
            const int mm = l >> 4, kk = l & 15;
            const int kg = k0 + kk;
            As[kk * 68 + mm] = (kg < K) ? A[(size_t)(m0 + mm) * K + kg] : 0.f;
            Bs[kk * 68 + mm] = (kg < K && (n0 + mm) < N)
                                   ? B[(size_t)(n0 + mm) * K + kg] : 0.f;
        }
        __syncthreads();
        #pragma unroll
        for (int kk = 0; kk < 16; ++kk) {
            const float4 av = *(const float4*)&As[kk * 68 + ty * 4];
            const float4 bv = *(const float4*)&Bs[kk * 68 + tx * 4];
            const float a[4] = {av.x, av.y, av.z, av.w};
            const float b[4] = {bv.x, bv.y, bv.z, bv.w};
            #pragma unroll
            for (int i = 0; i < 4; ++i)
                #pragma unroll
                for (int j = 0; j < 4; ++j)
                    acc[i][j] += a[i] * b[j];
        }
    }

    float bj[4];
    #pragma unroll
    for (int j = 0; j < 4; ++j) {
        const int n = n0 + tx * 4 + j;
        float bv = 0.f;
        if (n < N) {
            if (bias0) bv += bias0[n];
            if (bias1) bv += bias1[n];
        }
        bj[j] = bv;
    }
    #pragma unroll
    for (int i = 0; i < 4; ++i) {
        const int m = m0 + ty * 4 + i;
        #pragma unroll
        for (int j = 0; j < 4; ++j) {
            const int n = n0 + tx * 4 + j;
            if (n < N) C[(size_t)m * N + n] = acc[i][j] + bj[j];
        }
    }
}

// ---------------------------------------------------------------------------
// Fused 3-layer pipelined LSTM scan. 768 blocks x 512 threads, 3 blocks/CU.
//   layer = blockIdx>>8, b = blockIdx&255; block owns units u0=4b..4b+3.
//
// ROUND-7 (theory S: spill-induced L2/L3 saturation). R6's centralized
// detection regressed 6x (reverted). Theories E (poll mechanics) and G
// (detection cascade) are dead: three poll mechanics gave IDENTICAL 8.15us
// slots. What R0/R5 share: VGPR=84 against a 128-weight+~25-working layout
// -> ~70 floats/thread spilled; scratch reload ~55 MB/step / 8.1us ~= 6.8
// TB/s of L2/L3 traffic == fabric ceiling, invariant to poll changes,
// invisible in FETCH_SIZE (scratch is L3-resident). R1's "falsification" of
// S was confounded by its lag-32 chunk-GEMM stalls.
//
// Clean test: kill the spill, keep the rendezvous topology IDENTICAL (same
// 256 blocks/layer, same tagged-quad hbuf protocol, same 2 barriers/step).
//   * 512 threads (8 waves): wave w -> unit u0+(w>>1), half w&1 (0=ih,1=hh).
//     Each wave's 64 lanes cover the FULL 1024-dot of its half-matrix: 16
//     interleaved cols x 4 gates = 64 weight floats/thread. 64+~20 working
//     = 84 regs <= the __launch_bounds__(512,6) cap (~85) -> no spill, and
//     the hard cap guarantees 24 waves/CU = 3 blocks/CU residency (no
//     deadlock). Layer 0's ih-waves hold zero weights (keeps one code path).
//   * h staging split: threads 0..255 poll+stage own-layer h(t-1), threads
//     256..511 poll+stage lower-layer h(t) -- one quad per thread.
//   * butterfly per wave -> gsum[8][4]; wave0 lanes0..3 combine the two
//     half-sums per unit + add4 (xg for layer0 / biases for 1,2), then
//     elementwise + coalesced tagged-quad publish (R0's proven protocol).
// ---------------------------------------------------------------------------
__device__ __forceinline__ float sig_(float x) { return 1.f / (1.f + expf(-x)); }

__global__ __launch_bounds__(512, 6)
void lstm_fused(const float* __restrict__ xg,
                const float* __restrict__ Whh0,
                const float* __restrict__ Wih1, const float* __restrict__ Whh1,
                const float* __restrict__ bih1, const float* __restrict__ bhh1,
                const float* __restrict__ Wih2, const float* __restrict__ Whh2,
                const float* __restrict__ bih2, const float* __restrict__ bhh2,
                u64* __restrict__ hbuf0, u64* __restrict__ hbuf1,
                u64* __restrict__ hbuf2, float* __restrict__ hs2)
{
    __shared__ float hin_lds[HID];
    __shared__ float hprev_lds[HID];
    __shared__ float gsum[8][4];   // [wave][gate]; unit uloc = waves 2u,2u+1

    const int tid = threadIdx.x;
    const int w = tid >> 6, ln = tid & 63;
    const int uloc = w >> 1, half = w & 1;   // half: 0=ih, 1=hh
    const int layer = blockIdx.x >> 8;
    const int b = blockIdx.x & 255;
    const int u0 = 4 * b;
    const int unit = u0 + uloc;

    const float* Wih = (layer == 1) ? Wih1 : Wih2;                 // unused layer 0
    const float* Whh = (layer == 0) ? Whh0 : (layer == 1 ? Whh1 : Whh2);
    u64* hbI = (layer == 1) ? hbuf0 : hbuf1;                        // input-h buffer (layers 1,2)
    u64* hbP = (layer == 0) ? hbuf0 : (layer == 1 ? hbuf1 : hbuf2); // own-layer buffer

    // ---- weights: 4 gate-rows x 16 interleaved cols of ONE half-matrix ----
    // lane ln covers cols {ln + 64j}; LDS reads hit bank ln%32 for every j
    // (2 lanes/bank wave64 aliasing = free).
    float Wv[4][16];
    if (half == 0 && layer == 0) {
        #pragma unroll
        for (int g = 0; g < 4; ++g)
            #pragma unroll
            for (int j = 0; j < 16; ++j)
                Wv[g][j] = 0.f;
    } else {
        const float* M = half ? Whh : Wih;
        #pragma unroll
        for (int g = 0; g < 4; ++g) {
            const float* rp = M + (size_t)(g * HID + unit) * HID + ln;
            #pragma unroll
            for (int j = 0; j < 16; ++j)
                Wv[g][j] = rp[64 * j];
        }
    }

    // per-gate additive term: wave 0 lanes 0..3, lane ln handles unit u0+ln.
    float add4[4] = {0.f, 0.f, 0.f, 0.f};
    if (w == 0 && ln < 4 && layer > 0) {
        #pragma unroll
        for (int g = 0; g < 4; ++g) {
            const int r = g * HID + u0 + ln;
            add4[g] = (layer == 1) ? (bih1[r] + bhh1[r]) : (bih2[r] + bhh2[r]);
        }
    }

    const int sidx = tid & 255;
    const bool isP = (tid < 256);               // stager role: own-layer vs input
    const int p4 = 4 * ((sidx + b) & 255);      // block-rotated quad assignment

    if (layer == 0 && !isP)                     // hin stays exact zeros (layer 0)
        *(float4*)&hin_lds[p4] = make_float4(0.f, 0.f, 0.f, 0.f);

    float c = 0.f;   // cell state in wave-0 lanes 0..3
    for (int t = 0; t < TT; ++t) {
        if (layer == 0 && w == 0 && ln < 4) {   // x-gates prefetch (pre-poll)
            #pragma unroll
            for (int g = 0; g < 4; ++g)
                add4[g] = xg[(size_t)t * G4 + g * HID + u0 + ln];
        }

        // ---- acquire: each thread polls ONE quad of ONE buffer ----
        const bool need = isP ? (t > 0) : (layer > 0);
        if (need) {
            const u64* pp = isP ? (hbP + (size_t)(t - 1) * HID + p4)
                                : (hbI + (size_t)t * HID + p4);
            const u64 tag = isP ? (u64)(u32)t : (u64)(u32)(t + 1);
            u64 v0 = 0, v1 = 0, v2 = 0, v3 = 0;
            int guard = 0;
            for (;;) {
                v0 = __hip_atomic_load(pp + 0, __ATOMIC_RELAXED, __HIP_MEMORY_SCOPE_AGENT);
                if ((v0 >> 32) == tag) {   // sentinel hit: quad published together
                    v1 = __hip_atomic_load(pp + 1, __ATOMIC_RELAXED, __HIP_MEMORY_SCOPE_AGENT);
                    v2 = __hip_atomic_load(pp + 2, __ATOMIC_RELAXED, __HIP_MEMORY_SCOPE_AGENT);
                    v3 = __hip_atomic_load(pp + 3, __ATOMIC_RELAXED, __HIP_MEMORY_SCOPE_AGENT);
                    if ((v1 >> 32) == tag && (v2 >> 32) == tag && (v3 >> 32) == tag)
                        break;
                }
                if (++guard > (1 << 18)) break;   // anti-hang bailout (unreached when healthy)
                __builtin_amdgcn_s_sleep(1);      // ~64cy backoff
            }
            float* dst = isP ? hprev_lds : hin_lds;
            *(float4*)&dst[p4] = make_float4(
                __uint_as_float((unsigned)v0), __uint_as_float((unsigned)v1),
                __uint_as_float((unsigned)v2), __uint_as_float((unsigned)v3));
        } else if (isP) {   // t == 0: h(-1) = 0
            *(float4*)&hprev_lds[p4] = make_float4(0.f, 0.f, 0.f, 0.f);
        }
        __syncthreads();   // (1) h vectors staged

        // ---- matvec: 4 gate rows x 16 interleaved cols, weights in regs ----
        const float* hsrc = half ? hprev_lds : hin_lds;
        float a0 = 0.f, a1 = 0.f, a2 = 0.f, a3 = 0.f;
        #pragma unroll
        for (int j = 0; j < 16; ++j) {
            const float h = hsrc[ln + 64 * j];
            a0 += Wv[0][j] * h;
            a1 += Wv[1][j] * h;
            a2 += Wv[2][j] * h;
            a3 += Wv[3][j] * h;
        }
        // 64-lane butterfly: full 1024-col dot of this half-matrix per gate
        #pragma unroll
        for (int off = 1; off < 64; off <<= 1) {
            a0 += __shfl_xor(a0, off, 64);
            a1 += __shfl_xor(a1, off, 64);
            a2 += __shfl_xor(a2, off, 64);
            a3 += __shfl_xor(a3, off, 64);
        }
        if (ln == 0) {
            gsum[w][0] = a0; gsum[w][1] = a1; gsum[w][2] = a2; gsum[w][3] = a3;
        }
        __syncthreads();   // (2) gate half-sums exchanged; LDS safe next iter

        // ---- wave 0 lanes 0..3: combine halves + elementwise + publish ----
        if (w == 0 && ln < 4) {
            const float i_ = sig_(gsum[2 * ln][0] + gsum[2 * ln + 1][0] + add4[0]);
            const float f_ = sig_(gsum[2 * ln][1] + gsum[2 * ln + 1][1] + add4[1]);
            const float g_ = tanhf(gsum[2 * ln][2] + gsum[2 * ln + 1][2] + add4[2]);
            const float o_ = sig_(gsum[2 * ln][3] + gsum[2 * ln + 1][3] + add4[3]);
            c = f_ * c + i_ * g_;
            const float h = o_ * tanhf(c);
            if (layer == 2) hs2[(size_t)t * HID + u0 + ln] = h;
            const u64 pv = (((u64)(unsigned)(t + 1)) << 32) |
                           (u64)__float_as_uint(h);
            __hip_atomic_store(hbP + (size_t)t * HID + u0 + ln, pv,
                               __ATOMIC_RELAXED, __HIP_MEMORY_SCOPE_AGENT);
        }
        // Next iteration's poll gates every consumer on this publish; gsum is
        // rewritten only after the next barrier(1)+matvec, so no extra barrier.
    }
}

// ---------------------------------------------------------------------------
extern "C" void kernel_launch(void* const* d_in, const int* in_sizes, int n_in,
                              void* d_out, int out_size, void* d_ws, size_t ws_size,
                              hipStream_t stream)
{
    (void)in_sizes; (void)n_in; (void)out_size; (void)ws_size;

    const float* pose = (const float*)d_in[0];
    const float* Wih0 = (const float*)d_in[1];
    const float* Whh0 = (const float*)d_in[2];
    const float* bih0 = (const float*)d_in[3];
    const float* bhh0 = (const float*)d_in[4];
    const float* Wih1 = (const float*)d_in[5];
    const float* Whh1 = (const float*)d_in[6];
    const float* bih1 = (const float*)d_in[7];
    const float* bhh1 = (const float*)d_in[8];
    const float* Wih2 = (const float*)d_in[9];
    const float* Whh2 = (const float*)d_in[10];
    const float* bih2 = (const float*)d_in[11];
    const float* bhh2 = (const float*)d_in[12];
    const float* Wout = (const float*)d_in[13];
    float* out = (float*)d_out;

    // Workspace: hbuf0|hbuf1|hbuf2 (3 x 4 MB tagged u64) | xg (8 MB) | hs2 (2 MB)
    char* ws = (char*)d_ws;
    const size_t HB = (size_t)TT * HID * sizeof(u64);
    u64* hbuf0 = (u64*)ws;
    u64* hbuf1 = (u64*)(ws + HB);
    u64* hbuf2 = (u64*)(ws + 2 * HB);
    float* xg  = (float*)(ws + 3 * HB);
    float* hs2 = (float*)(ws + 3 * HB + (size_t)TT * G4 * sizeof(float));

    (void)hipMemsetAsync(hbuf0, 0, 3 * HB, stream);

    // layer-0 x-gates: [512,85] x [85,4096]^T (+ both biases)
    gemm_nt<<<dim3(G4 / 64, TT / 64), dim3(256), 0, stream>>>(
        pose, Wih0, bih0, bhh0, xg, TT, G4, INDIM);
    // fused pipelined 3-layer scan (512-thread blocks)
    lstm_fused<<<dim3(768), dim3(512), 0, stream>>>(
        xg, Whh0, Wih1, Whh1, bih1, bhh1, Wih2, Whh2, bih2, bhh2,
        hbuf0, hbuf1, hbuf2, hs2);
    // output projection: [512,1024] x [1024,20670]^T
    gemm_nt<<<dim3((NOUT + 63) / 64, TT / 64), dim3(256), 0, stream>>>(
        hs2, Wout, nullptr, nullptr, out, TT, NOUT, HID);
}

// Round 8
// 5075.348 us; speedup vs baseline: 5.2345x; 1.2101x over previous
//
#include <hip/hip_runtime.h>
#include <stdint.h>

#define TT    512
#define HID   1024
#define G4    4096
#define INDIM 85
#define NOUT  20670   // 6890*3

typedef unsigned long long u64;
typedef unsigned int u32;

// ---------------------------------------------------------------------------
// Tiled fp32 GEMM: C[M,N] = A[M,K] * B[N,K]^T + bias0 + bias1
// 64x64 tile, BK=16, 256 threads, 4x4 micro-tile per thread. (unchanged)
// ---------------------------------------------------------------------------
__global__ __launch_bounds__(256)
void gemm_nt(const float* __restrict__ A, const float* __restrict__ B,
             const float* __restrict__ bias0, const float* __restrict__ bias1,
             float* __restrict__ C, int M, int N, int K)
{
    __shared__ float As[16 * 68];
    __shared__ float Bs[16 * 68];
    const int tid = threadIdx.x;
    const int tx = tid & 15, ty = tid >> 4;
    const int m0 = blockIdx.y * 64, n0 = blockIdx.x * 64;
    float acc[4][4] = {};
    const int KT = (K + 15) >> 4;

    for (int kt = 0; kt < KT; ++kt) {
        const int k0 = kt << 4;
        __syncthreads();
        for (int l = tid; l < 1024; l += 256) {
            const int mm = l >> 4, kk = l & 15;
            const int kg = k0 + kk;
            As[kk * 68 + mm] = (kg < K) ? A[(size_t)(m0 + mm) * K + kg] : 0.f;
            Bs[kk * 68 + mm] = (kg < K && (n0 + mm) < N)
                                   ? B[(size_t)(n0 + mm) * K + kg] : 0.f;
        }
        __syncthreads();
        #pragma unroll
        for (int kk = 0; kk < 16; ++kk) {
            const float4 av = *(const float4*)&As[kk * 68 + ty * 4];
            const float4 bv = *(const float4*)&Bs[kk * 68 + tx * 4];
            const float a[4] = {av.x, av.y, av.z, av.w};
            const float b[4] = {bv.x, bv.y, bv.z, bv.w};
            #pragma unroll
            for (int i = 0; i < 4; ++i)
                #pragma unroll
                for (int j = 0; j < 4; ++j)
                    acc[i][j] += a[i] * b[j];
        }
    }

    float bj[4];
    #pragma unroll
    for (int j = 0; j < 4; ++j) {
        const int n = n0 + tx * 4 + j;
        float bv = 0.f;
        if (n < N) {
            if (bias0) bv += bias0[n];
            if (bias1) bv += bias1[n];
        }
        bj[j] = bv;
    }
    #pragma unroll
    for (int i = 0; i < 4; ++i) {
        const int m = m0 + ty * 4 + i;
        #pragma unroll
        for (int j = 0; j < 4; ++j) {
            const int n = n0 + tx * 4 + j;
            if (n < N) C[(size_t)m * N + n] = acc[i][j] + bj[j];
        }
    }
}

// ---------------------------------------------------------------------------
// Fused 3-layer pipelined LSTM scan. 768 blocks x 256 threads, 3 blocks/CU.
//   layer = blockIdx>>8, b = blockIdx&255; block owns units u0=4b..4b+3.
//
// ROUND-8 (theory S': weight re-streaming at the L3 BW wall). Evidence
// synthesis: R0/R5 report VGPR=84 against a 128-float weight layout -> LLVM
// SANK the loop-invariant __restrict__ weight loads into the t-loop
// (rematerialization) instead of holding them live across 512 iterations.
// Every step therefore re-reads ~84 MB of fp32 weights; 84MB/8.1us = 10.4
// TB/s == Infinity-Cache BW. Explains: slot invariance to poll mechanics
// (R0=R1=R5), VALUBusy 11% (waiting on L3 returns), low FETCH_SIZE (L3
// absorbs), and R7's regression when the stream partially fell to HBM
// (FETCH 3.4GB at VGPR cap 85).
//
// THE ONE CHANGE vs R5 (clean A/B): after loading, each weight float4 passes
// through an empty `asm volatile` with "+v" constraints. asm volatile cannot
// be sunk/duplicated/rematerialized -> the 128 weight floats must stay live
// (in the unified VGPR/AGPR file) across the whole t-loop. Budget: cap 170
// at __launch_bounds__(256,3); 128 pinned + ~40 working = ~168, fits.
// Expected: VGPR_Count ~165+, slot 8.1 -> 2-5us if S' holds; FETCH explosion
// (R7 signature) if the pin forces scratch spill; unchanged slot = weights
// exonerated -> exchange floor / roofline case.
// ---------------------------------------------------------------------------
__device__ __forceinline__ float sig_(float x) { return 1.f / (1.f + expf(-x)); }

__device__ __forceinline__ void sleep_k_(int k)
{
    switch (k) {
        case 0:  __builtin_amdgcn_s_sleep(1);  break;   // ~64 cy
        case 1:  __builtin_amdgcn_s_sleep(2);  break;
        case 2:  __builtin_amdgcn_s_sleep(4);  break;
        case 3:  __builtin_amdgcn_s_sleep(8);  break;
        default: __builtin_amdgcn_s_sleep(16); break;   // ~1024 cy cap
    }
}

__global__ __launch_bounds__(256, 3)
void lstm_fused(const float* __restrict__ xg,
                const float* __restrict__ Whh0,
                const float* __restrict__ Wih1, const float* __restrict__ Whh1,
                const float* __restrict__ bih1, const float* __restrict__ bhh1,
                const float* __restrict__ Wih2, const float* __restrict__ Whh2,
                const float* __restrict__ bih2, const float* __restrict__ bhh2,
                u64* __restrict__ hbuf0, u64* __restrict__ hbuf1,
                u64* __restrict__ hbuf2, float* __restrict__ hs2)
{
    __shared__ float hin_lds[HID];
    __shared__ float hprev_lds[HID];
    __shared__ float gsum[4][4];   // [wave/unit][gate]

    const int tid = threadIdx.x;
    const int w = tid >> 6, ln = tid & 63, q = ln & 31;
    const bool inHalf = (ln < 32);
    const int layer = blockIdx.x >> 8;
    const int b = blockIdx.x & 255;
    const int u0 = 4 * b;
    const int unit = u0 + w;

    const float* Wih = (layer == 1) ? Wih1 : Wih2;                 // unused for layer 0
    const float* Whh = (layer == 0) ? Whh0 : (layer == 1 ? Whh1 : Whh2);
    u64* hbI = (layer == 1) ? hbuf0 : hbuf1;                        // input-h buffer (layers 1,2)
    u64* hbP = (layer == 0) ? hbuf0 : (layer == 1 ? hbuf1 : hbuf2); // own-layer buffer

    // ---- stage weights: 4 gate-rows x 32 cols of one matrix per lane ----
    float4 Wv[4][8];
    if (layer == 0 && inHalf) {
        #pragma unroll
        for (int g = 0; g < 4; ++g)
            #pragma unroll
            for (int j = 0; j < 8; ++j)
                Wv[g][j] = make_float4(0.f, 0.f, 0.f, 0.f);
    } else {
        const float* M = inHalf ? Wih : Whh;
        #pragma unroll
        for (int g = 0; g < 4; ++g) {
            const float* rp = M + (size_t)(g * HID + unit) * HID + 4 * q;
            #pragma unroll
            for (int j = 0; j < 8; ++j)
                Wv[g][j] = *(const float4*)(rp + 128 * j);
        }
    }
    // ---- PIN: opaque identity asm -> loads cannot be sunk/remat'ed; the
    // 128 weight floats must stay live in the unified reg file all loop. ----
    #pragma unroll
    for (int g = 0; g < 4; ++g)
        #pragma unroll
        for (int j = 0; j < 8; ++j)
            asm volatile("" : "+v"(Wv[g][j].x), "+v"(Wv[g][j].y),
                              "+v"(Wv[g][j].z), "+v"(Wv[g][j].w));

    // per-gate additive term: WAVE 0 LANES 0..3, lane ln handles unit u0+ln.
    float add4[4] = {0.f, 0.f, 0.f, 0.f};
    if (w == 0 && ln < 4 && layer > 0) {
        #pragma unroll
        for (int g = 0; g < 4; ++g) {
            const int r = g * HID + u0 + ln;
            add4[g] = (layer == 1) ? (bih1[r] + bhh1[r]) : (bih2[r] + bhh2[r]);
        }
    }

    if (layer == 0) {   // W_ih half unused: keep hin_lds at exact zeros
        const int p4z = 4 * ((tid + b) & 255);
        *(float4*)&hin_lds[p4z] = make_float4(0.f, 0.f, 0.f, 0.f);
    }

    float c = 0.f;   // cell state in wave-0 lanes 0..3
    for (int t = 0; t < TT; ++t) {
        if (layer == 0 && w == 0 && ln < 4) {   // x-gates prefetch (pre-poll)
            #pragma unroll
            for (int g = 0; g < 4; ++g)
                add4[g] = xg[(size_t)t * G4 + g * HID + u0 + ln];
        }

        // ---- acquire h vectors (block-rotated unit assignment) ----
        const int p4 = 4 * ((tid + b) & 255);
        bool doneP = (t == 0), doneI = (layer == 0);
        u64 vp0 = 0, vp1 = 0, vp2 = 0, vp3 = 0;
        u64 vi0 = 0, vi1 = 0, vi2 = 0, vi3 = 0;
        const u32 tP32 = (u32)t;                    // hbP[t-1] carries tag t
        const u32 tI32 = (u32)(t + 1);              // hbI[t]   carries tag t+1
        const u64 tagP = (u64)tP32;
        const u64 tagI = (u64)tI32;
        const u64* pp = hbP + (size_t)(t - 1) * HID + p4;
        const u64* pi = hbI + (size_t)t * HID + p4;

        // ---- FAST PATH: one-shot plain cached reads, tag-verified ----
        if (!doneP) {
            const uint4 a  = *(const uint4*)(pp);       // quads 0,1
            const uint4 b2 = *(const uint4*)(pp + 2);   // quads 2,3
            if (a.y == tP32 && a.w == tP32 && b2.y == tP32 && b2.w == tP32) {
                vp0 = ((u64)a.y  << 32) | a.x;  vp1 = ((u64)a.w  << 32) | a.z;
                vp2 = ((u64)b2.y << 32) | b2.x; vp3 = ((u64)b2.w << 32) | b2.z;
                doneP = true;
            }
        }
        if (!doneI) {
            const uint4 a  = *(const uint4*)(pi);
            const uint4 b2 = *(const uint4*)(pi + 2);
            if (a.y == tI32 && a.w == tI32 && b2.y == tI32 && b2.w == tI32) {
                vi0 = ((u64)a.y  << 32) | a.x;  vi1 = ((u64)a.w  << 32) | a.z;
                vi2 = ((u64)b2.y << 32) | b2.x; vi3 = ((u64)b2.w << 32) | b2.z;
                doneI = true;
            }
        }

        // ---- SLOW PATH: R0 atomic poll (bypasses stale L2) + exp backoff --
        if (!(doneP && doneI)) {
            int guard = 0, k = 0;
            for (;;) {
                if (!doneP) {
                    vp0 = __hip_atomic_load(pp + 0, __ATOMIC_RELAXED, __HIP_MEMORY_SCOPE_AGENT);
                    if ((vp0 >> 32) == tagP) {   // sentinel hit: quad published together
                        vp1 = __hip_atomic_load(pp + 1, __ATOMIC_RELAXED, __HIP_MEMORY_SCOPE_AGENT);
                        vp2 = __hip_atomic_load(pp + 2, __ATOMIC_RELAXED, __HIP_MEMORY_SCOPE_AGENT);
                        vp3 = __hip_atomic_load(pp + 3, __ATOMIC_RELAXED, __HIP_MEMORY_SCOPE_AGENT);
                        doneP = (vp1 >> 32) == tagP && (vp2 >> 32) == tagP &&
                                (vp3 >> 32) == tagP;
                    }
                }
                if (!doneI) {
                    vi0 = __hip_atomic_load(pi + 0, __ATOMIC_RELAXED, __HIP_MEMORY_SCOPE_AGENT);
                    if ((vi0 >> 32) == tagI) {
                        vi1 = __hip_atomic_load(pi + 1, __ATOMIC_RELAXED, __HIP_MEMORY_SCOPE_AGENT);
                        vi2 = __hip_atomic_load(pi + 2, __ATOMIC_RELAXED, __HIP_MEMORY_SCOPE_AGENT);
                        vi3 = __hip_atomic_load(pi + 3, __ATOMIC_RELAXED, __HIP_MEMORY_SCOPE_AGENT);
                        doneI = (vi1 >> 32) == tagI && (vi2 >> 32) == tagI &&
                                (vi3 >> 32) == tagI;
                    }
                }
                if (doneP && doneI) break;
                if (++guard > (1 << 18)) break;   // anti-hang bailout (unreached when healthy)
                sleep_k_(k);                      // capped exp backoff: 64..1024cy
                if (k < 4) ++k;
            }
        }

        if (t == 0)
            *(float4*)&hprev_lds[p4] = make_float4(0.f, 0.f, 0.f, 0.f);
        else
            *(float4*)&hprev_lds[p4] = make_float4(
                __uint_as_float((unsigned)vp0), __uint_as_float((unsigned)vp1),
                __uint_as_float((unsigned)vp2), __uint_as_float((unsigned)vp3));
        if (layer > 0)
            *(float4*)&hin_lds[p4] = make_float4(
                __uint_as_float((unsigned)vi0), __uint_as_float((unsigned)vi1),
                __uint_as_float((unsigned)vi2), __uint_as_float((unsigned)vi3));
        __syncthreads();   // (1) h vectors staged

        // ---- matvec: 4 gate rows x 32 cols, weights in regs, h from LDS ----
        const float* hsrc = (inHalf ? hin_lds : hprev_lds) + 4 * q;
        float a0 = 0.f, a1 = 0.f, a2 = 0.f, a3 = 0.f;
        #pragma unroll
        for (int j = 0; j < 8; ++j) {
            const float4 hv = *(const float4*)(hsrc + 128 * j);
            a0 += Wv[0][j].x * hv.x + Wv[0][j].y * hv.y + Wv[0][j].z * hv.z + Wv[0][j].w * hv.w;
            a1 += Wv[1][j].x * hv.x + Wv[1][j].y * hv.y + Wv[1][j].z * hv.z + Wv[1][j].w * hv.w;
            a2 += Wv[2][j].x * hv.x + Wv[2][j].y * hv.y + Wv[2][j].z * hv.z + Wv[2][j].w * hv.w;
            a3 += Wv[3][j].x * hv.x + Wv[3][j].y * hv.y + Wv[3][j].z * hv.z + Wv[3][j].w * hv.w;
        }
        // 64-lane butterfly: sums ih-partials (lanes<32) + hh-partials (>=32)
        #pragma unroll
        for (int off = 1; off < 64; off <<= 1) {
            a0 += __shfl_xor(a0, off, 64);
            a1 += __shfl_xor(a1, off, 64);
            a2 += __shfl_xor(a2, off, 64);
            a3 += __shfl_xor(a3, off, 64);
        }
        if (ln == 0) {
            gsum[w][0] = a0; gsum[w][1] = a1; gsum[w][2] = a2; gsum[w][3] = a3;
        }
        __syncthreads();   // (2) gate sums exchanged; LDS safe to overwrite next iter

        // ---- wave 0 lanes 0..3: elementwise + COALESCED quad publish ----
        if (w == 0 && ln < 4) {
            const float i_ = sig_(gsum[ln][0] + add4[0]);
            const float f_ = sig_(gsum[ln][1] + add4[1]);
            const float g_ = tanhf(gsum[ln][2] + add4[2]);
            const float o_ = sig_(gsum[ln][3] + add4[3]);
            c = f_ * c + i_ * g_;
            const float h = o_ * tanhf(c);
            if (layer == 2) hs2[(size_t)t * HID + u0 + ln] = h;
            const u64 pv = (((u64)(unsigned)(t + 1)) << 32) |
                           (u64)__float_as_uint(h);
            __hip_atomic_store(hbP + (size_t)t * HID + u0 + ln, pv,
                               __ATOMIC_RELAXED, __HIP_MEMORY_SCOPE_AGENT);
        }
        // Next iteration's poll gates every consumer on this publish; gsum is
        // rewritten only after the next barrier(1)+matvec, so no extra barrier.
    }
}

// ---------------------------------------------------------------------------
extern "C" void kernel_launch(void* const* d_in, const int* in_sizes, int n_in,
                              void* d_out, int out_size, void* d_ws, size_t ws_size,
                              hipStream_t stream)
{
    (void)in_sizes; (void)n_in; (void)out_size; (void)ws_size;

    const float* pose = (const float*)d_in[0];
    const float* Wih0 = (const float*)d_in[1];
    const float* Whh0 = (const float*)d_in[2];
    const float* bih0 = (const float*)d_in[3];
    const float* bhh0 = (const float*)d_in[4];
    const float* Wih1 = (const float*)d_in[5];
    const float* Whh1 = (const float*)d_in[6];
    const float* bih1 = (const float*)d_in[7];
    const float* bhh1 = (const float*)d_in[8];
    const float* Wih2 = (const float*)d_in[9];
    const float* Whh2 = (const float*)d_in[10];
    const float* bih2 = (const float*)d_in[11];
    const float* bhh2 = (const float*)d_in[12];
    const float* Wout = (const float*)d_in[13];
    float* out = (float*)d_out;

    // Workspace: hbuf0|hbuf1|hbuf2 (3 x 4 MB tagged u64) | xg (8 MB) | hs2 (2 MB)
    char* ws = (char*)d_ws;
    const size_t HB = (size_t)TT * HID * sizeof(u64);
    u64* hbuf0 = (u64*)ws;
    u64* hbuf1 = (u64*)(ws + HB);
    u64* hbuf2 = (u64*)(ws + 2 * HB);
    float* xg  = (float*)(ws + 3 * HB);
    float* hs2 = (float*)(ws + 3 * HB + (size_t)TT * G4 * sizeof(float));

    (void)hipMemsetAsync(hbuf0, 0, 3 * HB, stream);

    const dim3 blk(256);
    // layer-0 x-gates: [512,85] x [85,4096]^T (+ both biases)
    gemm_nt<<<dim3(G4 / 64, TT / 64), blk, 0, stream>>>(
        pose, Wih0, bih0, bhh0, xg, TT, G4, INDIM);
    // fused pipelined 3-layer scan
    lstm_fused<<<dim3(768), blk, 0, stream>>>(
        xg, Whh0, Wih1, Whh1, bih1, bhh1, Wih2, Whh2, bih2, bhh2,
        hbuf0, hbuf1, hbuf2, hs2);
    // output projection: [512,1024] x [1024,20670]^T
    gemm_nt<<<dim3((NOUT + 63) / 64, TT / 64), blk, 0, stream>>>(
        hs2, Wout, nullptr, nullptr, out, TT, NOUT, HID);
}